// Round 7
// baseline (9022.931 us; speedup 1.0000x reference)
//
#include <hip/hip_runtime.h>
#include <hip/hip_bf16.h>
#include <stdint.h>

// AutoRegressive LSTM (B=1024, T=256, I=64, U=1024, S=64) on MI355X.
// R7: persistent per-XCD kernel, ZERO per-chunk barriers. A/B MFMA fragments
// loaded DIRECTLY global->VGPR (asm, compile-time vmcnt ledger, 3-slot FIFO,
// sc0 on recurrent data); B chunks 0..8 pinned in LDS (read-only after fill).
// Only sync per step: the per-XCD generation barrier.

typedef _Float16 f16;
typedef _Float16 f16x8 __attribute__((ext_vector_type(8)));
typedef float f32x4 __attribute__((ext_vector_type(4)));

#define NKW 17   // warmup K=1088 in BK=64 chunks (chunk0 = x)
#define NKD 16   // decode K=1024
#define LPIN 9   // chunks 0..8 pinned in LDS (144KB); 9+ streamed

struct StepCtx {
  const f16* hAb[4];   // A bases per mf (h rows, natural [row][1024])
  const f16* xAb[4];   // A bases per mf into x tile [row][64]
  const f16* Bst[4];   // streamed-B bases per nf ([col][K] layout)
  const f16* LdsB;
  int ldso[4];         // LDS col base offsets per nf
  int x7, ln4;
};

// ---- asm fragment loads (volatile: program-order among themselves) ----
template <bool WARM, int C>
__device__ __forceinline__ void issueA(const StepCtx& ctx, f16x8 (&afp)[3][2][4]) {
#pragma unroll
  for (int mf = 0; mf < 4; mf++) {
    if constexpr (WARM && C == 0) {
      asm volatile("global_load_dwordx4 %0, %1, off sc0"
                   : "=v"(afp[C % 3][0][mf]) : "v"(ctx.xAb[mf]));
      asm volatile("global_load_dwordx4 %0, %1, off offset:64 sc0"
                   : "=v"(afp[C % 3][1][mf]) : "v"(ctx.xAb[mf]));
    } else {
      constexpr int base = (WARM ? (C > 0 ? C - 1 : 0) : C) * 128;
      asm volatile("global_load_dwordx4 %0, %1, off offset:%2 sc0"
                   : "=v"(afp[C % 3][0][mf]) : "v"(ctx.hAb[mf]), "n"(base));
      asm volatile("global_load_dwordx4 %0, %1, off offset:%2 sc0"
                   : "=v"(afp[C % 3][1][mf]) : "v"(ctx.hAb[mf]), "n"(base + 64));
    }
  }
}

template <int C>
__device__ __forceinline__ void issueB(const StepCtx& ctx, f16x8 (&bsp)[3][2][4]) {
#pragma unroll
  for (int nf = 0; nf < 4; nf++) {
    asm volatile("global_load_dwordx4 %0, %1, off offset:%2"
                 : "=v"(bsp[C % 3][0][nf]) : "v"(ctx.Bst[nf]), "n"(C * 128));
    asm volatile("global_load_dwordx4 %0, %1, off offset:%2"
                 : "=v"(bsp[C % 3][1][nf]) : "v"(ctx.Bst[nf]), "n"(C * 128 + 64));
  }
}

// outstanding-after-target count for chunk c (all K-loop VMEM is ours)
constexpr int ledgerN(int c, int nk) {
  int n = 0;
  if (c + 1 < nk) { n++; if (c + 1 >= LPIN) n++; }
  if (c + 2 < nk) { n++; if (c + 2 >= LPIN) n++; }
  return 8 * n;
}

template <int NK, bool WARM, int C>
__device__ __forceinline__ void kstep(const StepCtx& ctx, f16x8 (&afp)[3][2][4],
                                      f16x8 (&bsp)[3][2][4], f32x4 (&acc)[4][4]) {
  if constexpr (C < NK) {
    if constexpr (C + 2 < NK) issueA<WARM, C + 2>(ctx, afp);
    if constexpr (C + 2 < NK && C + 2 >= LPIN) issueB<C + 2>(ctx, bsp);
    asm volatile("s_waitcnt vmcnt(%0)" :: "n"(ledgerN(C, NK)));
    __builtin_amdgcn_sched_barrier(0);
#pragma unroll
    for (int kc = 0; kc < 2; kc++) {
      f16x8 bf[4];
      if constexpr (C < LPIN) {
#pragma unroll
        for (int nf = 0; nf < 4; nf++)
          bf[nf] = *(const f16x8*)(ctx.LdsB + C * 8192 + ctx.ldso[nf] +
                                   8 * ((4 * kc + ctx.ln4) ^ ctx.x7));
      } else {
#pragma unroll
        for (int nf = 0; nf < 4; nf++) bf[nf] = bsp[C % 3][kc][nf];
      }
      __builtin_amdgcn_s_setprio(1);
#pragma unroll
      for (int mf = 0; mf < 4; mf++)
#pragma unroll
        for (int nf = 0; nf < 4; nf++)
          acc[mf][nf] = __builtin_amdgcn_mfma_f32_16x16x32_f16(afp[C % 3][kc][mf], bf[nf],
                                                               acc[mf][nf], 0, 0, 0);
      __builtin_amdgcn_s_setprio(0);
    }
  }
}

template <int NK, bool WARM>
__device__ __forceinline__ void kloop(const StepCtx& ctx, f32x4 (&acc)[4][4]) {
  f16x8 afp[3][2][4];
  f16x8 bsp[3][2][4];
  issueA<WARM, 0>(ctx, afp);
  issueA<WARM, 1>(ctx, afp);
#define KS_(C) kstep<NK, WARM, C>(ctx, afp, bsp, acc);
  KS_(0) KS_(1) KS_(2) KS_(3) KS_(4) KS_(5) KS_(6) KS_(7) KS_(8)
  KS_(9) KS_(10) KS_(11) KS_(12) KS_(13) KS_(14) KS_(15) KS_(16)
#undef KS_
}

// fill the LDS pinned-B image (swizzled) from [col][KS] weights
__device__ __forceinline__ void fill_lds(const f16* __restrict__ Wsrc, int KS,
                                         f16* LdsB, int tid) {
  for (int idx = tid; idx < LPIN * 1024; idx += 256) {
    const int cc = idx >> 10, rem = idx & 1023, col = rem >> 3, g = rem & 7;
    const f16x8 v = *(const f16x8*)(Wsrc + (size_t)col * KS + 64 * cc + 8 * g);
    *(f16x8*)(LdsB + cc * 8192 + col * 64 + 8 * (g ^ (col & 7))) = v;
  }
}

__device__ __forceinline__ float sigf(float x) { return 1.0f / (1.0f + __expf(-x)); }
__device__ __forceinline__ float tanhfast(float x) { return 1.0f - 2.0f / (__expf(2.0f * x) + 1.0f); }

// ---------------- persistent LSTM kernel ----------------
// grid 256, block 256 (4 waves), 144KB LDS -> 1 WG/CU, 32 WGs/XCD.
__global__ void __launch_bounds__(256, 1) lstm_persist(
    const f16* __restrict__ WT, const f16* __restrict__ WPT,
    const float* __restrict__ inputs,
    f16* __restrict__ hbA, f16* __restrict__ xbuf,
    float* __restrict__ ppart,
    const float* __restrict__ bperm, const float* __restrict__ bperm2,
    const float* __restrict__ Wd, const float* __restrict__ bd,
    const int* __restrict__ oidx, float* __restrict__ out,
    int n_idx, unsigned* __restrict__ bar) {
  const int tid = threadIdx.x;

  __shared__ __align__(16) f16 LdsB[LPIN * 8192];   // 147,456 B
  __shared__ unsigned rank_sh;

  unsigned xcd;
  asm("s_getreg_b32 %0, hwreg(HW_REG_XCC_ID)" : "=s"(xcd));
  xcd &= 7u;
  unsigned* rank_ctr = bar;            // [xcd*16]
  unsigned* bar_cnt = bar + 128;       // [xcd*16]
  unsigned* bar_gen = bar + 256;       // [xcd*16]
  if (tid == 0)
    rank_sh = __hip_atomic_fetch_add(&rank_ctr[xcd * 16], 1u, __ATOMIC_RELAXED,
                                     __HIP_MEMORY_SCOPE_AGENT) & 31u;
  __syncthreads();
  const int mi = (int)xcd;
  const int ni = (int)rank_sh;

  const int w = tid >> 6, lane = tid & 63;
  const int rw = w >> 1, cw = w & 1, ln15 = lane & 15, ln4 = lane >> 4;
  const int u_glob = 32 * ni + 16 * cw + ln15;
  (void)w;

  // biases + Wd cols for the output head
  float biw[4], bi2[4];
#pragma unroll
  for (int nf = 0; nf < 4; nf++) {
    biw[nf] = bperm[ni * 128 + 64 * cw + 16 * nf + ln15];
    bi2[nf] = bperm2[ni * 128 + 64 * cw + 16 * nf + ln15];
  }
  float wdj[8];
#pragma unroll
  for (int j = 0; j < 8; j++) wdj[j] = 0.f;
  for (int j = 0; j < n_idx; j++) wdj[j] = Wd[(size_t)u_glob * 64 + oidx[j]];

  float cst[4][4];
#pragma unroll
  for (int a = 0; a < 4; a++)
#pragma unroll
    for (int q = 0; q < 4; q++) cst[a][q] = 0.f;

  // static ctx pieces
  StepCtx ctx;
  ctx.LdsB = LdsB;
  ctx.x7 = ln15 & 7;
  ctx.ln4 = ln4;
  int rowm[4];
#pragma unroll
  for (int mf = 0; mf < 4; mf++) rowm[mf] = 64 * rw + 16 * mf + ln15;
#pragma unroll
  for (int nf = 0; nf < 4; nf++) ctx.ldso[nf] = (64 * cw + 16 * nf + ln15) * 64;

  // initial LDS pin fill (warm weights) + stream bases
  const f16* Wsw = WT + (size_t)ni * 128 * 1088;
  const f16* Wsd = WPT + (size_t)ni * 128 * 1024;
  fill_lds(Wsw, 1088, LdsB, tid);
#pragma unroll
  for (int nf = 0; nf < 4; nf++)
    ctx.Bst[nf] = Wsw + (size_t)(64 * cw + 16 * nf + ln15) * 1088 + ln4 * 8;
  __syncthreads();

  for (int t = 0; t < 319; ++t) {
    // ---- per-XCD barrier ----
    if (tid == 0 && t > 0) {
      int guard = 0;
      while (__hip_atomic_load(&bar_gen[xcd * 16], __ATOMIC_RELAXED,
                               __HIP_MEMORY_SCOPE_AGENT) < (unsigned)t) {
        __builtin_amdgcn_s_sleep(2);
        if (++guard > (1 << 26)) break;
      }
    }
    __builtin_amdgcn_s_barrier();

    const bool warm = (t < 256);

    // ---- decode entry: swap pinned/stream weights to W' ----
    if (t == 256) {
      fill_lds(Wsd, 1024, LdsB, tid);
#pragma unroll
      for (int nf = 0; nf < 4; nf++)
        ctx.Bst[nf] = Wsd + (size_t)(64 * cw + 16 * nf + ln15) * 1024 + ln4 * 8;
      __syncthreads();
    }

    const f16* hA = hbA + (size_t)((t & 1) * 8 + mi) * 131072;
    f16* hW = hbA + (size_t)(((t + 1) & 1) * 8 + mi) * 131072;
    const f16* xb = xbuf + (size_t)((t & 1) * 8 + mi) * 8192;
#pragma unroll
    for (int mf = 0; mf < 4; mf++) {
      ctx.hAb[mf] = hA + (size_t)rowm[mf] * 1024 + ln4 * 8;
      ctx.xAb[mf] = xb + (size_t)rowm[mf] * 64 + ln4 * 8;
    }

    // ---- reduce previous decode step's output partials ----
    if (t >= 256) {
      const int s = t - 256;
      const int sb = (t - 1) & 1;
      if (tid < 4 * n_idx) {
        const int row = 4 * ni + (tid & 3);
        const int j = tid >> 2;
        float acc2 = bd[oidx[j]];
        for (int q = 0; q < 32; q++) {
#pragma unroll
          for (int c2 = 0; c2 < 2; c2++) {
            const size_t idx = ((((size_t)(sb * 8 + mi) * 32 + q) * 8 + j) * 2 + c2) * 128 + row;
            acc2 += __hip_atomic_load(&ppart[idx], __ATOMIC_RELAXED, __HIP_MEMORY_SCOPE_AGENT);
          }
        }
        out[((size_t)(128 * mi + row) * 64 + s) * n_idx + j] = acc2;
      }
    }
    asm volatile("s_waitcnt vmcnt(0)" ::: "memory");   // clean VMEM queue for the ledger

    f32x4 acc[4][4];
#pragma unroll
    for (int a = 0; a < 4; a++)
#pragma unroll
      for (int q = 0; q < 4; q++) acc[a][q] = (f32x4){0.f, 0.f, 0.f, 0.f};

    if (warm) kloop<NKW, true>(ctx, acc);
    else      kloop<NKD, false>(ctx, acc);

    // ---- epilogue: gates -> c (regs), h (natural layout) ----
    const float b0 = warm ? biw[0] : bi2[0];
    const float b1 = warm ? biw[1] : bi2[1];
    const float b2v = warm ? biw[2] : bi2[2];
    const float b3 = warm ? biw[3] : bi2[3];
    float hv[4][4];
#pragma unroll
    for (int mf = 0; mf < 4; mf++) {
#pragma unroll
      for (int reg = 0; reg < 4; reg++) {
        const int rl = 64 * rw + 16 * mf + 4 * ln4 + reg;
        const float zi = acc[mf][0][reg] + b0;
        const float zf = acc[mf][1][reg] + b1;
        const float zg = acc[mf][2][reg] + b2v;
        const float zo = acc[mf][3][reg] + b3;
        const float cn = sigf(zf) * cst[mf][reg] + sigf(zi) * tanhfast(zg);
        const float hn = sigf(zo) * tanhfast(cn);
        cst[mf][reg] = cn;
        hv[mf][reg] = hn;
        hW[(size_t)rl * 1024 + u_glob] = (f16)hn;
      }
    }

    // ---- decode output partials ----
    if (t >= 255) {
      const int sbw = t & 1;
      for (int j = 0; j < n_idx; j++) {
        const float wd = wdj[j];
#pragma unroll
        for (int mf = 0; mf < 4; mf++)
#pragma unroll
          for (int reg = 0; reg < 4; reg++) {
            float v = hv[mf][reg] * wd;
            v += __shfl_xor(v, 1);
            v += __shfl_xor(v, 2);
            v += __shfl_xor(v, 4);
            v += __shfl_xor(v, 8);
            if (ln15 == 0) {
              const int rl = 64 * rw + 16 * mf + 4 * ln4 + reg;
              const size_t idx = ((((size_t)(sbw * 8 + mi) * 32 + ni) * 8 + j) * 2 + cw) * 128 + rl;
              ppart[idx] = v;
            }
          }
      }
    }

    // ---- x-tile prep for next warm step (rank 0 CU), natural layout ----
    if (warm && (t + 1 < 256) && ni == 0) {
      const int r = tid >> 1, cx = tid & 1;
      const float* src = inputs + (size_t)(128 * mi + r) * 16384 + (size_t)(t + 1) * 64 + cx * 32;
      f16* xo = xbuf + (size_t)(((t + 1) & 1) * 8 + mi) * 8192 + (size_t)r * 64 + cx * 32;
#pragma unroll
      for (int q = 0; q < 4; q++) {
        const float4 a = *(const float4*)(src + q * 8);
        const float4 bq = *(const float4*)(src + q * 8 + 4);
        f16x8 v;
        v[0] = (f16)a.x; v[1] = (f16)a.y; v[2] = (f16)a.z; v[3] = (f16)a.w;
        v[4] = (f16)bq.x; v[5] = (f16)bq.y; v[6] = (f16)bq.z; v[7] = (f16)bq.w;
        *(f16x8*)(xo + 8 * q) = v;
      }
    }

    // ---- drain, arrive ----
    asm volatile("s_waitcnt vmcnt(0)" ::: "memory");
    __builtin_amdgcn_s_barrier();
    if (tid == 0) {
      unsigned old = __hip_atomic_fetch_add(&bar_cnt[xcd * 16], 1u, __ATOMIC_RELAXED,
                                            __HIP_MEMORY_SCOPE_AGENT);
      if ((old & 31u) == 31u)
        __hip_atomic_fetch_add(&bar_gen[xcd * 16], 1u, __ATOMIC_RELAXED,
                               __HIP_MEMORY_SCOPE_AGENT);
    }
  }

  // ---- final: reduce s=63 partials ----
  if (tid == 0) {
    int guard = 0;
    while (__hip_atomic_load(&bar_gen[xcd * 16], __ATOMIC_RELAXED,
                             __HIP_MEMORY_SCOPE_AGENT) < 319u) {
      __builtin_amdgcn_s_sleep(2);
      if (++guard > (1 << 26)) break;
    }
  }
  __builtin_amdgcn_s_barrier();
  if (tid < 4 * n_idx) {
    const int row = 4 * ni + (tid & 3);
    const int j = tid >> 2;
    float acc2 = bd[oidx[j]];
    for (int q = 0; q < 32; q++) {
#pragma unroll
      for (int c2 = 0; c2 < 2; c2++) {
        const size_t idx = ((((size_t)mi * 32 + q) * 8 + j) * 2 + c2) * 128 + row;
        acc2 += __hip_atomic_load(&ppart[idx], __ATOMIC_RELAXED, __HIP_MEMORY_SCOPE_AGENT);
      }
    }
    out[((size_t)(128 * mi + row) * 64 + 63) * n_idx + j] = acc2;
  }
}

// ---------------- prep kernels ----------------
// WT[ni][n(0..127)][K=1088] fp16 col-major-K; n -> source col via gate interleave
__global__ void __launch_bounds__(256) prep_WT(const float* __restrict__ Wk,
                                               const float* __restrict__ Wr,
                                               f16* __restrict__ WT) {
  const int ni = blockIdx.x >> 3, seg = blockIdx.x & 7;
  for (int idx = threadIdx.x; idx < 16 * 136; idx += 256) {
    const int nloc = idx / 136, t8 = idx % 136;
    const int n = seg * 16 + nloc;
    const int nf = n >> 4, j = n & 15;
    const int col = (nf & 3) * 1024 + 32 * ni + 16 * (nf >> 2) + j;
    const int k0 = t8 * 8;
    f16x8 v;
#pragma unroll
    for (int e = 0; e < 8; e++) {
      const int kr = k0 + e;
      const float val = (kr < 64) ? Wk[(size_t)kr * 4096 + col]
                                  : Wr[(size_t)(kr - 64) * 4096 + col];
      v[e] = (f16)val;
    }
    *(f16x8*)(WT + (size_t)(ni * 128 + n) * 1088 + k0) = v;
  }
}

// WPT = (Wd@Wk + Wr), [ni][n][1024]
__global__ void __launch_bounds__(256) prep_WPT(const float* __restrict__ Wk,
                                                const float* __restrict__ Wr,
                                                const float* __restrict__ Wd,
                                                f16* __restrict__ WPT) {
  const int ni = blockIdx.x >> 3, seg = blockIdx.x & 7;
  for (int idx = threadIdx.x; idx < 16 * 128; idx += 256) {
    const int nloc = idx >> 7, t8 = idx & 127;
    const int n = seg * 16 + nloc;
    const int nf = n >> 4, j = n & 15;
    const int col = (nf & 3) * 1024 + 32 * ni + 16 * (nf >> 2) + j;
    const int k0 = t8 * 8;
    float accv[8];
#pragma unroll
    for (int e = 0; e < 8; e++) accv[e] = Wr[(size_t)(k0 + e) * 4096 + col];
#pragma unroll
    for (int i = 0; i < 64; i++) {
      const float wki = Wk[(size_t)i * 4096 + col];
#pragma unroll
      for (int e = 0; e < 8; e++)
        accv[e] += Wd[(size_t)(k0 + e) * 64 + i] * wki;
    }
    f16x8 v;
#pragma unroll
    for (int e = 0; e < 8; e++) v[e] = (f16)accv[e];
    *(f16x8*)(WPT + (size_t)(ni * 128 + n) * 1024 + k0) = v;
  }
}

__global__ void __launch_bounds__(256) prep_b(const float* __restrict__ b, float* __restrict__ bperm) {
  const int x = blockIdx.x * 256 + threadIdx.x;  // 4096
  const int ni = x >> 7, rem = x & 127, nf = rem >> 4, j = rem & 15;
  bperm[x] = b[(nf & 3) * 1024 + 32 * ni + 16 * (nf >> 2) + j];
}

__global__ void __launch_bounds__(256) prep_b2(const float* __restrict__ b,
                                               const float* __restrict__ bd,
                                               const float* __restrict__ Wk,
                                               float* __restrict__ bperm2) {
  const int x = blockIdx.x * 256 + threadIdx.x;  // 4096
  const int ni = x >> 7, rem = x & 127, nf = rem >> 4, j = rem & 15;
  const int col = (nf & 3) * 1024 + 32 * ni + 16 * (nf >> 2) + j;
  float acc = b[col];
#pragma unroll
  for (int i = 0; i < 64; i++) acc += bd[i] * Wk[(size_t)i * 4096 + col];
  bperm2[x] = acc;
}

// x tile for t=0, natural [row][64]
__global__ void __launch_bounds__(256) prep_x0(const float* __restrict__ inp, f16* __restrict__ xbuf) {
  const int mi = blockIdx.x, tid = threadIdx.x;
  const int r = tid >> 1, cx = tid & 1;
  const float* src = inp + (size_t)(128 * mi + r) * 16384 + cx * 32;
  f16* xo = xbuf + (size_t)mi * 8192 + (size_t)r * 64 + cx * 32;
#pragma unroll
  for (int q = 0; q < 4; q++) {
    const float4 a = *(const float4*)(src + q * 8);
    const float4 b = *(const float4*)(src + q * 8 + 4);
    f16x8 v;
    v[0] = (f16)a.x; v[1] = (f16)a.y; v[2] = (f16)a.z; v[3] = (f16)a.w;
    v[4] = (f16)b.x; v[5] = (f16)b.y; v[6] = (f16)b.z; v[7] = (f16)b.w;
    *(f16x8*)(xo + 8 * q) = v;
  }
}

// ---------------- host ----------------
extern "C" void kernel_launch(void* const* d_in, const int* in_sizes, int n_in,
                              void* d_out, int out_size, void* d_ws, size_t ws_size,
                              hipStream_t stream) {
  (void)in_sizes; (void)n_in;
  const float* inputs = (const float*)d_in[0];
  const float* Wk = (const float*)d_in[1];
  const float* Wr = (const float*)d_in[2];
  const float* bv = (const float*)d_in[3];
  const float* Wd = (const float*)d_in[4];
  const float* bd = (const float*)d_in[5];
  const int* oidx = (const int*)d_in[6];
  float* out = (float*)d_out;
  const int n_idx = out_size / (1024 * 64);
  if (n_idx < 1 || n_idx > 8) return;

  char* ws = (char*)d_ws;
  const size_t OFF_WT = 0;                  // 32*128*1088*2 = 8,912,896
  const size_t OFF_WPT = 8912896;           // 32*128*1024*2 = 8,388,608
  const size_t OFF_BPERM = 17301504;        // 16,384
  const size_t OFF_BPERM2 = 17317888;       // 16,384
  const size_t OFF_HA = 17334272;           // 2*8*128*1024*2 = 4,194,304
  const size_t OFF_XB = 21528576;           // 2*8*128*64*2 = 262,144
  const size_t OFF_PP = 21790720;           // 4,194,304
  const size_t OFF_BAR = 25985024;          // 4,096
  const size_t NEED = 25989120;
  if (ws_size < NEED) return;

  f16* WT = (f16*)(ws + OFF_WT);
  f16* WPT = (f16*)(ws + OFF_WPT);
  float* bperm = (float*)(ws + OFF_BPERM);
  float* bperm2 = (float*)(ws + OFF_BPERM2);
  f16* hbA = (f16*)(ws + OFF_HA);
  f16* xbuf = (f16*)(ws + OFF_XB);
  float* ppart = (float*)(ws + OFF_PP);
  unsigned* bar = (unsigned*)(ws + OFF_BAR);

  hipMemsetAsync(hbA, 0, 2097152, stream);   // h parity-0 = zeros
  hipMemsetAsync(bar, 0, 4096, stream);
  hipLaunchKernelGGL(prep_WT, dim3(256), dim3(256), 0, stream, Wk, Wr, WT);
  hipLaunchKernelGGL(prep_WPT, dim3(256), dim3(256), 0, stream, Wk, Wr, Wd, WPT);
  hipLaunchKernelGGL(prep_b, dim3(16), dim3(256), 0, stream, bv, bperm);
  hipLaunchKernelGGL(prep_b2, dim3(16), dim3(256), 0, stream, bv, bd, Wk, bperm2);
  hipLaunchKernelGGL(prep_x0, dim3(8), dim3(256), 0, stream, inputs, xbuf);

  hipLaunchKernelGGL(lstm_persist, dim3(256), dim3(256), 0, stream,
                     (const f16*)WT, (const f16*)WPT, inputs,
                     hbA, xbuf, ppart,
                     (const float*)bperm, (const float*)bperm2,
                     Wd, bd, oidx, out, n_idx, bar);
}

// Round 8
// 6668.911 us; speedup vs baseline: 1.3530x; 1.3530x over previous
//
#include <hip/hip_runtime.h>
#include <hip/hip_bf16.h>
#include <stdint.h>

// AutoRegressive LSTM (B=1024, T=256, I=64, U=1024, S=64) on MI355X.
// R8: persistent per-XCD kernel, 512 threads (8 waves = 2/SIMD for TLP).
// All operands staged through LDS once (no per-wave dup): 3-buf A + 3-buf B,
// 2-deep counted-vmcnt ledger, 3 B-chunks LDS-pinned, weights pre-swizzled
// (linear staging), A staged via per-lane swizzled source from natural h.

typedef _Float16 f16;
typedef _Float16 f16x8 __attribute__((ext_vector_type(8)));
typedef float f32x4 __attribute__((ext_vector_type(4)));

#define NKW 17   // warmup K chunks (chunk0 = x)
#define NKD 16   // decode K chunks
#define PIN 3    // B chunks 0..2 pinned in LDS
#define CHH 8192 // halves per [128][64] tile (16KB)

__device__ __forceinline__ void gl_lds_a(const char* src_lane, const f16* dst_wave) {
  __builtin_amdgcn_global_load_lds(
      (const __attribute__((address_space(1))) unsigned int*)src_lane,
      (__attribute__((address_space(3))) unsigned int*)dst_wave, 16, 0, 1);  // sc0: L1 bypass
}
__device__ __forceinline__ void gl_lds_w(const char* src_lane, const f16* dst_wave) {
  __builtin_amdgcn_global_load_lds(
      (const __attribute__((address_space(1))) unsigned int*)src_lane,
      (__attribute__((address_space(3))) unsigned int*)dst_wave, 16, 0, 0);
}

__device__ __forceinline__ float sigf(float x) { return 1.0f / (1.0f + __expf(-x)); }
__device__ __forceinline__ float tanhfast(float x) { return 1.0f - 2.0f / (__expf(2.0f * x) + 1.0f); }

// ---------------- persistent LSTM kernel ----------------
// grid 256 x 512 threads (8 waves), 144KB LDS -> 1 WG/CU, 32 WGs/XCD.
// mi = physical XCD (rows 128mi..+127), ni = per-XCD rank (units 32ni..+31).
// Wave w: rw=w>>1 (32 rows), cw=w&1 (64 gate-cols).
__global__ void __launch_bounds__(512, 1) lstm_persist(
    const f16* __restrict__ WT, const f16* __restrict__ WPT,
    const float* __restrict__ inputs,
    f16* __restrict__ hbA, f16* __restrict__ xbuf,
    float* __restrict__ ppart,
    const float* __restrict__ bperm, const float* __restrict__ bperm2,
    const float* __restrict__ Wd, const float* __restrict__ bd,
    const int* __restrict__ oidx, float* __restrict__ out,
    int n_idx, unsigned* __restrict__ bar) {
  const int tid = threadIdx.x;

  __shared__ __align__(16) f16 WpL[PIN * CHH];   // 48KB pinned B
  __shared__ __align__(16) f16 Abuf[3][CHH];     // 48KB
  __shared__ __align__(16) f16 Bbuf[3][CHH];     // 48KB  (total 144KB)
  __shared__ unsigned rank_sh;

  unsigned xcd;
  asm("s_getreg_b32 %0, hwreg(HW_REG_XCC_ID)" : "=s"(xcd));
  xcd &= 7u;
  unsigned* rank_ctr = bar;            // [xcd*16]
  unsigned* bar_cnt = bar + 128;       // [xcd*16]
  unsigned* bar_gen = bar + 256;       // [xcd*16]
  if (tid == 0)
    rank_sh = __hip_atomic_fetch_add(&rank_ctr[xcd * 16], 1u, __ATOMIC_RELAXED,
                                     __HIP_MEMORY_SCOPE_AGENT) & 31u;
  __syncthreads();
  const int mi = (int)xcd;
  const int ni = (int)rank_sh;

  const int w = tid >> 6, lane = tid & 63;
  const int rw = w >> 1, cw = w & 1, ln15 = lane & 15, ln4 = lane >> 4;
  const int u_glob = 32 * ni + 16 * cw + ln15;

  // staging lane constants (row&7 == (lane>>3)&7 for both A halves)
  const int l3 = lane >> 3, g8 = lane & 7;
  const int gsw = g8 ^ (l3 & 7);
  const int row_s = w * 8 + l3;  // rows row_s (j=0) and row_s+64 (j=1)
  const size_t hoff0 = (size_t)row_s * 2048 + (size_t)gsw * 16;
  const size_t hoff1 = (size_t)(row_s + 64) * 2048 + (size_t)gsw * 16;
  const size_t xoff0 = (size_t)row_s * 128 + (size_t)gsw * 16;
  const size_t xoff1 = (size_t)(row_s + 64) * 128 + (size_t)gsw * 16;

  // biases + Wd cols for the output head
  float biw[4], bi2[4];
#pragma unroll
  for (int nf = 0; nf < 4; nf++) {
    biw[nf] = bperm[ni * 128 + 64 * cw + 16 * nf + ln15];
    bi2[nf] = bperm2[ni * 128 + 64 * cw + 16 * nf + ln15];
  }
  float wdj[8];
#pragma unroll
  for (int j = 0; j < 8; j++) wdj[j] = 0.f;
  for (int j = 0; j < n_idx; j++) wdj[j] = Wd[(size_t)u_glob * 64 + oidx[j]];

  float cst[2][4];
#pragma unroll
  for (int a = 0; a < 2; a++)
#pragma unroll
    for (int q = 0; q < 4; q++) cst[a][q] = 0.f;

  const char* Wsw = (const char*)(WT + (size_t)ni * NKW * CHH);
  const char* Wsd = (const char*)(WPT + (size_t)ni * NKD * CHH);

  // staging lambdas
  auto stageA = [&](int c, const char* hbytes, const char* xbytes, bool warmf) {
    f16* slot = Abuf[c % 3];
    if (warmf && c == 0) {
      gl_lds_a(xbytes + xoff0, slot + w * 512);
      gl_lds_a(xbytes + xoff1, slot + 4096 + w * 512);
    } else {
      const char* base = hbytes + (size_t)(warmf ? c - 1 : c) * 128;
      gl_lds_a(base + hoff0, slot + w * 512);
      gl_lds_a(base + hoff1, slot + 4096 + w * 512);
    }
  };
  auto stageB = [&](const char* panel, int c) {
    f16* slot = Bbuf[c % 3];
    const char* src = panel + (size_t)c * 16384 + (size_t)w * 1024 + (size_t)lane * 16;
    gl_lds_w(src, slot + w * 512);
    gl_lds_w(src + 8192, slot + 4096 + w * 512);
  };
  auto fillPin = [&](const char* panel) {
#pragma unroll
    for (int i = 0; i < 6; i++)
      gl_lds_w(panel + (size_t)(i * 8 + w) * 1024 + (size_t)lane * 16,
               WpL + (i * 8 + w) * 512);
  };

  // initial pinned fill (warm weights)
  fillPin(Wsw);
  asm volatile("s_waitcnt vmcnt(0)" ::: "memory");
  __syncthreads();

  for (int t = 0; t < 319; ++t) {
    // ---- per-XCD barrier ----
    if (tid == 0 && t > 0) {
      int guard = 0;
      while (__hip_atomic_load(&bar_gen[xcd * 16], __ATOMIC_RELAXED,
                               __HIP_MEMORY_SCOPE_AGENT) < (unsigned)t) {
        __builtin_amdgcn_s_sleep(2);
        if (++guard > (1 << 26)) break;
      }
    }
    __builtin_amdgcn_s_barrier();

    const bool warm = (t < 256);
    const char* hA = (const char*)(hbA + (size_t)((t & 1) * 8 + mi) * 131072);
    f16* hW = hbA + (size_t)(((t + 1) & 1) * 8 + mi) * 131072;
    const char* xb = (const char*)(xbuf + (size_t)((t & 1) * 8 + mi) * CHH);
    const char* panel = warm ? Wsw : Wsd;

    // ---- parallel reduce of previous decode step's output partials ----
    if (t >= 256) {
      const int s = t - 256;
      const int sb = (t - 1) & 1;
      const int nwork = 4 * n_idx * 8;
      if (tid < nwork) {
        const int qg = tid & 7, rj = tid >> 3;
        const int j = rj % n_idx, r4 = rj / n_idx;
        const int row = 4 * ni + r4;
        float a2 = 0.f;
#pragma unroll
        for (int qq = 0; qq < 4; qq++) {
          const int q = 4 * qg + qq;
#pragma unroll
          for (int c2 = 0; c2 < 2; c2++) {
            const size_t idx = ((((size_t)(sb * 8 + mi) * 32 + q) * 8 + j) * 2 + c2) * 128 + row;
            a2 += __hip_atomic_load(&ppart[idx], __ATOMIC_RELAXED, __HIP_MEMORY_SCOPE_AGENT);
          }
        }
        a2 += __shfl_xor(a2, 1);
        a2 += __shfl_xor(a2, 2);
        a2 += __shfl_xor(a2, 4);
        if (qg == 0) out[((size_t)(128 * mi + row) * 64 + s) * n_idx + j] = a2 + bd[oidx[j]];
      }
    }
    // ---- decode entry: swap pinned B to W' ----
    if (t == 256) fillPin(Wsd);
    asm volatile("s_waitcnt vmcnt(0)" ::: "memory");
    __builtin_amdgcn_s_barrier();

    f32x4 acc[2][4];
#pragma unroll
    for (int a = 0; a < 2; a++)
#pragma unroll
      for (int q = 0; q < 4; q++) acc[a][q] = (f32x4){0.f, 0.f, 0.f, 0.f};

    // ---- K loop: counted-vmcnt, barrier, issue c+2, compute c ----
    const int NK = warm ? NKW : NKD;
    stageA(0, hA, xb, warm);
    stageA(1, hA, xb, warm);
#pragma unroll 1
    for (int c = 0; c < NK; ++c) {
      if (c + 1 >= NK)      asm volatile("s_waitcnt vmcnt(0)" ::: "memory");
      else if (c + 1 < PIN) asm volatile("s_waitcnt vmcnt(2)" ::: "memory");
      else                  asm volatile("s_waitcnt vmcnt(4)" ::: "memory");
      __builtin_amdgcn_s_barrier();
      __builtin_amdgcn_sched_barrier(0);
      if (c + 2 < NK) {
        stageA(c + 2, hA, xb, warm);
        if (c + 2 >= PIN) stageB(panel, c + 2);
      }
      const f16* Ab = Abuf[c % 3];
      const f16* Bb = (c < PIN) ? (WpL + c * CHH) : Bbuf[c % 3];
#pragma unroll
      for (int kc = 0; kc < 2; kc++) {
        const int gx = ((4 * kc + ln4) ^ (ln15 & 7)) * 8;
        f16x8 af[2], bf[4];
#pragma unroll
        for (int mf = 0; mf < 2; mf++)
          af[mf] = *(const f16x8*)(Ab + (32 * rw + 16 * mf + ln15) * 64 + gx);
#pragma unroll
        for (int nf = 0; nf < 4; nf++)
          bf[nf] = *(const f16x8*)(Bb + (64 * cw + 16 * nf + ln15) * 64 + gx);
        __builtin_amdgcn_s_setprio(1);
#pragma unroll
        for (int mf = 0; mf < 2; mf++)
#pragma unroll
          for (int nf = 0; nf < 4; nf++)
            acc[mf][nf] = __builtin_amdgcn_mfma_f32_16x16x32_f16(af[mf], bf[nf], acc[mf][nf], 0, 0, 0);
        __builtin_amdgcn_s_setprio(0);
      }
    }

    // ---- epilogue: gates -> c (regs), h (natural [row][1024]) ----
    const float b0 = warm ? biw[0] : bi2[0];
    const float b1 = warm ? biw[1] : bi2[1];
    const float b2v = warm ? biw[2] : bi2[2];
    const float b3 = warm ? biw[3] : bi2[3];
    float hv[2][4];
#pragma unroll
    for (int mf = 0; mf < 2; mf++) {
#pragma unroll
      for (int reg = 0; reg < 4; reg++) {
        const int r = 32 * rw + 16 * mf + 4 * ln4 + reg;
        const float zi = acc[mf][0][reg] + b0;
        const float zf = acc[mf][1][reg] + b1;
        const float zg = acc[mf][2][reg] + b2v;
        const float zo = acc[mf][3][reg] + b3;
        const float cn = sigf(zf) * cst[mf][reg] + sigf(zi) * tanhfast(zg);
        const float hn = sigf(zo) * tanhfast(cn);
        cst[mf][reg] = cn;
        hv[mf][reg] = hn;
        hW[(size_t)r * 1024 + u_glob] = (f16)hn;
      }
    }

    // ---- x-tile prep for next warm step (rank 0 CU), natural [row][64] ----
    if (warm && (t + 1 < 256) && ni == 0) {
      const int r = tid >> 2, k0 = (tid & 3) * 16;
      const float* src = inputs + (size_t)(128 * mi + r) * 16384 + (size_t)(t + 1) * 64 + k0;
      f16* xo = xbuf + (size_t)(((t + 1) & 1) * 8 + mi) * CHH + (size_t)r * 64 + k0;
#pragma unroll
      for (int h2 = 0; h2 < 2; h2++) {
        const float4 a = *(const float4*)(src + h2 * 8);
        const float4 bq = *(const float4*)(src + h2 * 8 + 4);
        f16x8 v;
        v[0] = (f16)a.x; v[1] = (f16)a.y; v[2] = (f16)a.z; v[3] = (f16)a.w;
        v[4] = (f16)bq.x; v[5] = (f16)bq.y; v[6] = (f16)bq.z; v[7] = (f16)bq.w;
        *(f16x8*)(xo + 8 * h2) = v;
      }
    }

    // ---- decode output partials ----
    if (t >= 255) {
      const int sbw = t & 1;
      for (int j = 0; j < n_idx; j++) {
        const float wd = wdj[j];
#pragma unroll
        for (int mf = 0; mf < 2; mf++)
#pragma unroll
          for (int reg = 0; reg < 4; reg++) {
            float v = hv[mf][reg] * wd;
            v += __shfl_xor(v, 1);
            v += __shfl_xor(v, 2);
            v += __shfl_xor(v, 4);
            v += __shfl_xor(v, 8);
            if (ln15 == 0) {
              const int r = 32 * rw + 16 * mf + 4 * ln4 + reg;
              const size_t idx = ((((size_t)(sbw * 8 + mi) * 32 + ni) * 8 + j) * 2 + cw) * 128 + r;
              ppart[idx] = v;
            }
          }
      }
    }

    // ---- drain, arrive ----
    asm volatile("s_waitcnt vmcnt(0)" ::: "memory");
    __builtin_amdgcn_s_barrier();
    if (tid == 0) {
      unsigned old = __hip_atomic_fetch_add(&bar_cnt[xcd * 16], 1u, __ATOMIC_RELAXED,
                                            __HIP_MEMORY_SCOPE_AGENT);
      if ((old & 31u) == 31u)
        __hip_atomic_fetch_add(&bar_gen[xcd * 16], 1u, __ATOMIC_RELAXED,
                               __HIP_MEMORY_SCOPE_AGENT);
    }
  }

  // ---- final: reduce s=63 partials ----
  if (tid == 0) {
    int guard = 0;
    while (__hip_atomic_load(&bar_gen[xcd * 16], __ATOMIC_RELAXED,
                             __HIP_MEMORY_SCOPE_AGENT) < 319u) {
      __builtin_amdgcn_s_sleep(2);
      if (++guard > (1 << 26)) break;
    }
  }
  __builtin_amdgcn_s_barrier();
  {
    const int nwork = 4 * n_idx * 8;
    if (tid < nwork) {
      const int qg = tid & 7, rj = tid >> 3;
      const int j = rj % n_idx, r4 = rj / n_idx;
      const int row = 4 * ni + r4;
      float a2 = 0.f;
#pragma unroll
      for (int qq = 0; qq < 4; qq++) {
        const int q = 4 * qg + qq;
#pragma unroll
        for (int c2 = 0; c2 < 2; c2++) {
          const size_t idx = ((((size_t)mi * 32 + q) * 8 + j) * 2 + c2) * 128 + row;
          a2 += __hip_atomic_load(&ppart[idx], __ATOMIC_RELAXED, __HIP_MEMORY_SCOPE_AGENT);
        }
      }
      a2 += __shfl_xor(a2, 1);
      a2 += __shfl_xor(a2, 2);
      a2 += __shfl_xor(a2, 4);
      if (qg == 0) out[((size_t)(128 * mi + row) * 64 + 63) * n_idx + j] = a2 + bd[oidx[j]];
    }
  }
}

// ---------------- prep kernels ----------------
// WT[ni][c][col][g] swizzled: halves ((ni*17+c)*128+col)*64 + g*8 + e
//   = W[k = 64c + 8*(g^(col&7)) + e][gatecol(ni,col)]
__global__ void __launch_bounds__(256) prep_WT(const float* __restrict__ Wk,
                                               const float* __restrict__ Wr,
                                               f16* __restrict__ WT) {
  const int blk = blockIdx.x;  // ni*17 + c
  const int ni = blk / NKW, c = blk % NKW;
  f16* ob = WT + (size_t)blk * CHH;
  for (int it = threadIdx.x; it < 1024; it += 256) {
    const int col = it >> 3, g = it & 7;
    const int nf = col >> 4, j = col & 15;
    const int gcol = (nf & 3) * 1024 + 32 * ni + 16 * (nf >> 2) + j;
    const int k0 = 64 * c + 8 * (g ^ (col & 7));
    f16x8 v;
#pragma unroll
    for (int e = 0; e < 8; e++) {
      const int kr = k0 + e;
      const float val = (kr < 64) ? Wk[(size_t)kr * 4096 + gcol]
                                  : Wr[(size_t)(kr - 64) * 4096 + gcol];
      v[e] = (f16)val;
    }
    *(f16x8*)(ob + col * 64 + g * 8) = v;
  }
}

// WPT = (Wd@Wk + Wr), same swizzled layout, K=1024
__global__ void __launch_bounds__(256) prep_WPT(const float* __restrict__ Wk,
                                                const float* __restrict__ Wr,
                                                const float* __restrict__ Wd,
                                                f16* __restrict__ WPT) {
  const int blk = blockIdx.x;  // ni*16 + c
  const int ni = blk / NKD, c = blk % NKD;
  f16* ob = WPT + (size_t)blk * CHH;
  for (int it = threadIdx.x; it < 1024; it += 256) {
    const int col = it >> 3, g = it & 7;
    const int nf = col >> 4, j = col & 15;
    const int gcol = (nf & 3) * 1024 + 32 * ni + 16 * (nf >> 2) + j;
    const int k0 = 64 * c + 8 * (g ^ (col & 7));
    float accv[8];
#pragma unroll
    for (int e = 0; e < 8; e++) accv[e] = Wr[(size_t)(k0 + e) * 4096 + gcol];
#pragma unroll
    for (int i = 0; i < 64; i++) {
      const float wki = Wk[(size_t)i * 4096 + gcol];
#pragma unroll
      for (int e = 0; e < 8; e++)
        accv[e] += Wd[(size_t)(k0 + e) * 64 + i] * wki;
    }
    f16x8 v;
#pragma unroll
    for (int e = 0; e < 8; e++) v[e] = (f16)accv[e];
    *(f16x8*)(ob + col * 64 + g * 8) = v;
  }
}

__global__ void __launch_bounds__(256) prep_b(const float* __restrict__ b, float* __restrict__ bperm) {
  const int x = blockIdx.x * 256 + threadIdx.x;  // 4096
  const int ni = x >> 7, rem = x & 127, nf = rem >> 4, j = rem & 15;
  bperm[x] = b[(nf & 3) * 1024 + 32 * ni + 16 * (nf >> 2) + j];
}

__global__ void __launch_bounds__(256) prep_b2(const float* __restrict__ b,
                                               const float* __restrict__ bd,
                                               const float* __restrict__ Wk,
                                               float* __restrict__ bperm2) {
  const int x = blockIdx.x * 256 + threadIdx.x;  // 4096
  const int ni = x >> 7, rem = x & 127, nf = rem >> 4, j = rem & 15;
  const int col = (nf & 3) * 1024 + 32 * ni + 16 * (nf >> 2) + j;
  float acc = b[col];
#pragma unroll
  for (int i = 0; i < 64; i++) acc += bd[i] * Wk[(size_t)i * 4096 + col];
  bperm2[x] = acc;
}

// x tile for t=0, natural [row][64]
__global__ void __launch_bounds__(256) prep_x0(const float* __restrict__ inp, f16* __restrict__ xbuf) {
  const int mi = blockIdx.x, tid = threadIdx.x;
  const int r = tid >> 1, c0 = (tid & 1) * 32;
  const float* src = inp + (size_t)(128 * mi + r) * 16384 + c0;
  f16* xo = xbuf + (size_t)mi * CHH + (size_t)r * 64 + c0;
#pragma unroll
  for (int q = 0; q < 4; q++) {
    const float4 a = *(const float4*)(src + q * 8);
    const float4 b = *(const float4*)(src + q * 8 + 4);
    f16x8 v;
    v[0] = (f16)a.x; v[1] = (f16)a.y; v[2] = (f16)a.z; v[3] = (f16)a.w;
    v[4] = (f16)b.x; v[5] = (f16)b.y; v[6] = (f16)b.z; v[7] = (f16)b.w;
    *(f16x8*)(xo + 8 * q) = v;
  }
}

// ---------------- host ----------------
extern "C" void kernel_launch(void* const* d_in, const int* in_sizes, int n_in,
                              void* d_out, int out_size, void* d_ws, size_t ws_size,
                              hipStream_t stream) {
  (void)in_sizes; (void)n_in;
  const float* inputs = (const float*)d_in[0];
  const float* Wk = (const float*)d_in[1];
  const float* Wr = (const float*)d_in[2];
  const float* bv = (const float*)d_in[3];
  const float* Wd = (const float*)d_in[4];
  const float* bd = (const float*)d_in[5];
  const int* oidx = (const int*)d_in[6];
  float* out = (float*)d_out;
  const int n_idx = out_size / (1024 * 64);
  if (n_idx < 1 || n_idx > 8) return;

  char* ws = (char*)d_ws;
  const size_t OFF_WT = 0;                  // 32*17*16KB = 8,912,896
  const size_t OFF_WPT = 8912896;           // 32*16*16KB = 8,388,608
  const size_t OFF_BPERM = 17301504;        // 16,384
  const size_t OFF_BPERM2 = 17317888;       // 16,384
  const size_t OFF_HA = 17334272;           // 2*8*128*1024*2 = 4,194,304
  const size_t OFF_XB = 21528576;           // 2*8*8192*2 = 262,144
  const size_t OFF_PP = 21790720;           // 4,194,304
  const size_t OFF_BAR = 25985024;          // 4,096
  const size_t NEED = 25989120;
  if (ws_size < NEED) return;

  f16* WT = (f16*)(ws + OFF_WT);
  f16* WPT = (f16*)(ws + OFF_WPT);
  float* bperm = (float*)(ws + OFF_BPERM);
  float* bperm2 = (float*)(ws + OFF_BPERM2);
  f16* hbA = (f16*)(ws + OFF_HA);
  f16* xbuf = (f16*)(ws + OFF_XB);
  float* ppart = (float*)(ws + OFF_PP);
  unsigned* bar = (unsigned*)(ws + OFF_BAR);

  hipMemsetAsync(hbA, 0, 2097152, stream);   // h parity-0 = zeros
  hipMemsetAsync(bar, 0, 4096, stream);
  hipLaunchKernelGGL(prep_WT, dim3(32 * NKW), dim3(256), 0, stream, Wk, Wr, WT);
  hipLaunchKernelGGL(prep_WPT, dim3(32 * NKD), dim3(256), 0, stream, Wk, Wr, Wd, WPT);
  hipLaunchKernelGGL(prep_b, dim3(16), dim3(256), 0, stream, bv, bperm);
  hipLaunchKernelGGL(prep_b2, dim3(16), dim3(256), 0, stream, bv, bd, Wk, bperm2);
  hipLaunchKernelGGL(prep_x0, dim3(8), dim3(256), 0, stream, inputs, xbuf);

  hipLaunchKernelGGL(lstm_persist, dim3(256), dim3(512), 0, stream,
                     (const f16*)WT, (const f16*)WPT, inputs,
                     hbA, xbuf, ppart,
                     (const float*)bperm, (const float*)bperm2,
                     Wd, bd, oidx, out, n_idx, bar);
}